// Round 2
// baseline (2340.935 us; speedup 1.0000x reference)
//
#include <hip/hip_runtime.h>

#define NB 8
#define CIN 512
#define CO 128
#define NS 16
#define NHW 4096
#define NR 3
#define NK 64
#define KMITERS 10

// ---------------------------------------------------------------------------
// Tiled 1x1-conv GEMM: out[g,m,n] = sum_c W[m,c] * X[g,c,n] + bias[m]
// X: (G, CIN, NHW) fp32, W: (O, CIN) fp32.
// ---------------------------------------------------------------------------
template<int BM, int BN, int BK, int TM, int TN>
__global__ __launch_bounds__(256) void conv1x1(const float* __restrict__ X,
    const float* __restrict__ Wt, const float* __restrict__ bias,
    float* __restrict__ outf)
{
    __shared__ float sW[BK][BM + 1];
    __shared__ float sX[BK][BN + 1];
    const int g  = blockIdx.z;
    const int m0 = blockIdx.y * BM;
    const int n0 = blockIdx.x * BN;
    const int tid = threadIdx.x;
    const int tn = tid % (BN / TN);
    const int tm = tid / (BN / TN);
    const int O = gridDim.y * BM;

    float acc[TM][TN];
#pragma unroll
    for (int i = 0; i < TM; ++i)
#pragma unroll
        for (int j = 0; j < TN; ++j) acc[i][j] = 0.f;

    for (int c0 = 0; c0 < CIN; c0 += BK) {
#pragma unroll
        for (int idx = tid; idx < BM * BK; idx += 256) {
            int k = idx % BK, i = idx / BK;
            sW[k][i] = Wt[(size_t)(m0 + i) * CIN + c0 + k];
        }
#pragma unroll
        for (int idx = tid; idx < BK * BN; idx += 256) {
            int j = idx % BN, k = idx / BN;
            sX[k][j] = X[((size_t)g * CIN + c0 + k) * NHW + n0 + j];
        }
        __syncthreads();
#pragma unroll
        for (int k = 0; k < BK; ++k) {
            float a[TM], bb[TN];
#pragma unroll
            for (int i = 0; i < TM; ++i) a[i] = sW[k][tm * TM + i];
#pragma unroll
            for (int j = 0; j < TN; ++j) bb[j] = sX[k][tn * TN + j];
#pragma unroll
            for (int i = 0; i < TM; ++i)
#pragma unroll
                for (int j = 0; j < TN; ++j) acc[i][j] = fmaf(a[i], bb[j], acc[i][j]);
        }
        __syncthreads();
    }
#pragma unroll
    for (int i = 0; i < TM; ++i) {
        int m = m0 + tm * TM + i;
        float bv = bias[m];
#pragma unroll
        for (int j = 0; j < TN; ++j) {
            int n = n0 + tn * TN + j;
            outf[((size_t)g * O + m) * NHW + n] = acc[i][j] + bv;
        }
    }
}

// ---------------------------------------------------------------------------
// KMeans
// ---------------------------------------------------------------------------
__global__ void km_init(const float* __restrict__ xt, float* __restrict__ cent) {
    int idx = blockIdx.x * 256 + threadIdx.x;
    if (idx >= NB * NK * CO) return;
    int c = idx % CO;
    int k = (idx / CO) % NK;
    int b = idx / (CO * NK);
    cent[idx] = xt[((size_t)b * CO + c) * NHW + 65 * k];
}

// One block = 256 points of one batch item. Labels against current centroids,
// accumulates per-cluster sums/counts (LDS then global atomics).
__global__ __launch_bounds__(256) void km_assign(const float* __restrict__ xt,
    const float* __restrict__ cent, float* __restrict__ sums, float* __restrict__ cnt)
{
    __shared__ float sbuf[NK * (CO + 1)];  // phase1: centroids (stride CO); phase2: sums (stride CO+1)
    __shared__ float sC2[NK];
    __shared__ float sCnt[NK];
    const int b = blockIdx.y;
    const int tid = threadIdx.x;

    for (int i = tid; i < NK * CO; i += 256) sbuf[i] = cent[(size_t)b * NK * CO + i];
    __syncthreads();
    if (tid < NK) {
        float s = 0.f;
        for (int c = 0; c < CO; ++c) { float v = sbuf[tid * CO + c]; s = fmaf(v, v, s); }
        sC2[tid] = s;
    }
    __syncthreads();

    const int n = blockIdx.x * 256 + tid;
    float dot[NK];
#pragma unroll
    for (int k = 0; k < NK; ++k) dot[k] = 0.f;
    float p2 = 0.f;
    for (int c0 = 0; c0 < CO; c0 += 4) {
        float v0 = xt[((size_t)b * CO + c0 + 0) * NHW + n];
        float v1 = xt[((size_t)b * CO + c0 + 1) * NHW + n];
        float v2 = xt[((size_t)b * CO + c0 + 2) * NHW + n];
        float v3 = xt[((size_t)b * CO + c0 + 3) * NHW + n];
        p2 += v0 * v0 + v1 * v1 + v2 * v2 + v3 * v3;
#pragma unroll
        for (int k = 0; k < NK; ++k) {
            const float4 c4 = *reinterpret_cast<const float4*>(&sbuf[k * CO + c0]);
            dot[k] += v0 * c4.x + v1 * c4.y + v2 * c4.z + v3 * c4.w;
        }
    }
    int lab = 0;
    float bd = p2 + sC2[0] - 2.f * dot[0];
#pragma unroll
    for (int k = 1; k < NK; ++k) {
        float d = p2 + sC2[k] - 2.f * dot[k];
        if (d < bd) { bd = d; lab = k; }  // strict <  == numpy first-min argmin
    }
    __syncthreads();  // done reading centroids; reuse sbuf as sums
    for (int i = tid; i < NK * (CO + 1); i += 256) sbuf[i] = 0.f;
    if (tid < NK) sCnt[tid] = 0.f;
    __syncthreads();
    // stride CO+1=129 so scattered-lab atomics spread across banks
    for (int c0 = 0; c0 < CO; c0 += 4) {
        float v0 = xt[((size_t)b * CO + c0 + 0) * NHW + n];
        float v1 = xt[((size_t)b * CO + c0 + 1) * NHW + n];
        float v2 = xt[((size_t)b * CO + c0 + 2) * NHW + n];
        float v3 = xt[((size_t)b * CO + c0 + 3) * NHW + n];
        atomicAdd(&sbuf[lab * (CO + 1) + c0 + 0], v0);
        atomicAdd(&sbuf[lab * (CO + 1) + c0 + 1], v1);
        atomicAdd(&sbuf[lab * (CO + 1) + c0 + 2], v2);
        atomicAdd(&sbuf[lab * (CO + 1) + c0 + 3], v3);
    }
    atomicAdd(&sCnt[lab], 1.f);
    __syncthreads();
    for (int i = tid; i < NK * CO; i += 256) {
        int k = i / CO, c = i % CO;
        atomicAdd(&sums[(size_t)b * NK * CO + i], sbuf[k * (CO + 1) + c]);
    }
    if (tid < NK) atomicAdd(&cnt[b * NK + tid], sCnt[tid]);
}

// grid = NB*NK blocks, 128 threads; also re-zeroes sums/counts for next iter.
__global__ void km_update(float* __restrict__ cent, float* __restrict__ sums,
                          float* __restrict__ cnt)
{
    int bk = blockIdx.x;
    int c = threadIdx.x;
    float cn = cnt[bk];
    float s = sums[(size_t)bk * CO + c];
    __syncthreads();
    if (cn > 0.f) cent[(size_t)bk * CO + c] = s / fmaxf(cn, 1.f);
    sums[(size_t)bk * CO + c] = 0.f;
    if (c == 0) cnt[bk] = 0.f;
}

// ---------------------------------------------------------------------------
// Slot branch: softmax over S=16 (dim 1). Reads raw from ssb, writes probs out4.
// ---------------------------------------------------------------------------
__global__ void slot_softmax(const float* __restrict__ ssb, float* __restrict__ out4) {
    int idx = blockIdx.x * 256 + threadIdx.x;
    if (idx >= NB * NHW) return;
    int b = idx / NHW, n = idx % NHW;
    float v[NS];
    float m = -1e30f;
#pragma unroll
    for (int s = 0; s < NS; ++s) { v[s] = ssb[((size_t)b * NS + s) * NHW + n]; m = fmaxf(m, v[s]); }
    float sum = 0.f;
#pragma unroll
    for (int s = 0; s < NS; ++s) { v[s] = expf(v[s] - m); sum += v[s]; }
    float inv = 1.f / sum;
#pragma unroll
    for (int s = 0; s < NS; ++s)
        out4[((size_t)b * NS + s) * NHW + n] = v[s] * inv;
}

// slot_pt[b,s,c] = sum_n ss[b,s,n] * xt[b,c,n]  (atomic fp32 accumulation)
__global__ __launch_bounds__(256) void slot_pt_kernel(const float* __restrict__ ss,
    const float* __restrict__ xt, float* __restrict__ spt)
{
    __shared__ float sS[NS][257];
    __shared__ float sX[32][257];
    const int b = blockIdx.y;
    const int n0 = blockIdx.x * 256;
    const int tid = threadIdx.x;
    for (int i = tid; i < NS * 256; i += 256) {
        int s = i >> 8, nn = i & 255;
        sS[s][nn] = ss[((size_t)b * NS + s) * NHW + n0 + nn];
    }
    const int c = tid & 31;
    const int sA = tid >> 5;  // 0..7
    for (int cg = 0; cg < 4; ++cg) {
        __syncthreads();
        for (int i = tid; i < 32 * 256; i += 256) {
            int cc = i >> 8, nn = i & 255;
            sX[cc][nn] = xt[((size_t)b * CO + cg * 32 + cc) * NHW + n0 + nn];
        }
        __syncthreads();
        float a0 = 0.f, a1 = 0.f;
        for (int nn = 0; nn < 256; ++nn) {
            float x = sX[c][nn];
            a0 = fmaf(x, sS[sA][nn], a0);
            a1 = fmaf(x, sS[sA + 8][nn], a1);
        }
        atomicAdd(&spt[((size_t)b * NS + sA) * CO + cg * 32 + c], a0);
        atomicAdd(&spt[((size_t)b * NS + sA + 8) * CO + cg * 32 + c], a1);
    }
}

// ---------------------------------------------------------------------------
// Ref branch: per-row (g,c) max & inverse softmax denom over NHW
// ---------------------------------------------------------------------------
__global__ __launch_bounds__(256) void rowstats(const float* __restrict__ xr,
    float* __restrict__ rmax, float* __restrict__ rinv)
{
    const int row = blockIdx.x;  // NR*NB*CO rows
    const float* p = xr + (size_t)row * NHW;
    const int tid = threadIdx.x;
    float v[16];
    float m = -1e30f;
#pragma unroll
    for (int i = 0; i < 16; ++i) { v[i] = p[tid + (i << 8)]; m = fmaxf(m, v[i]); }
#pragma unroll
    for (int off = 32; off; off >>= 1) m = fmaxf(m, __shfl_down(m, off));
    __shared__ float sm[4];
    __shared__ float ss2[4];
    const int wid = tid >> 6, lane = tid & 63;
    if (lane == 0) sm[wid] = m;
    __syncthreads();
    m = fmaxf(fmaxf(sm[0], sm[1]), fmaxf(sm[2], sm[3]));
    float s = 0.f;
#pragma unroll
    for (int i = 0; i < 16; ++i) s += expf(v[i] - m);
#pragma unroll
    for (int off = 32; off; off >>= 1) s += __shfl_down(s, off);
    if (lane == 0) ss2[wid] = s;
    __syncthreads();
    if (tid == 0) {
        rmax[row] = m;
        rinv[row] = 1.f / (ss2[0] + ss2[1] + ss2[2] + ss2[3]);
    }
}

// ref_pt[g,c,d] = sum_n softmax_row(c)[n] * xr[g,d,n]; softmax applied on the fly
__global__ __launch_bounds__(256) void refpt_gemm(const float* __restrict__ xr,
    const float* __restrict__ rmax, const float* __restrict__ rinv,
    float* __restrict__ refpt)
{
    constexpr int BM = 32, BN = 32, BK = 64, TM = 2, TN = 2;
    __shared__ float sS[BK][BM + 1];
    __shared__ float sX[BK][BN + 1];
    const int g = blockIdx.z;
    const int c0 = blockIdx.y * BM, d0 = blockIdx.x * BN;
    const int tid = threadIdx.x;
    const int tn = tid % (BN / TN), tm = tid / (BN / TN);
    const float* base = xr + (size_t)g * CO * NHW;
    float acc[TM][TN] = {{0.f, 0.f}, {0.f, 0.f}};
    for (int n0 = 0; n0 < NHW; n0 += BK) {
#pragma unroll
        for (int idx = tid; idx < BM * BK; idx += 256) {
            int k = idx % BK, i = idx / BK;
            int row = c0 + i;
            float vv = base[(size_t)row * NHW + n0 + k];
            sS[k][i] = expf(vv - rmax[g * CO + row]) * rinv[g * CO + row];
        }
#pragma unroll
        for (int idx = tid; idx < BN * BK; idx += 256) {
            int k = idx % BK, j = idx / BK;
            sX[k][j] = base[(size_t)(d0 + j) * NHW + n0 + k];
        }
        __syncthreads();
#pragma unroll
        for (int k = 0; k < BK; ++k) {
            float a0 = sS[k][tm * TM], a1 = sS[k][tm * TM + 1];
            float b0 = sX[k][tn * TN], b1 = sX[k][tn * TN + 1];
            acc[0][0] = fmaf(a0, b0, acc[0][0]);
            acc[0][1] = fmaf(a0, b1, acc[0][1]);
            acc[1][0] = fmaf(a1, b0, acc[1][0]);
            acc[1][1] = fmaf(a1, b1, acc[1][1]);
        }
        __syncthreads();
    }
#pragma unroll
    for (int i = 0; i < TM; ++i) {
        int cc = c0 + tm * TM + i;
#pragma unroll
        for (int j = 0; j < TN; ++j) {
            int dd = d0 + tn * TN + j;
            refpt[((size_t)g * CO + cc) * CO + dd] = acc[i][j];
        }
    }
}

// ---------------------------------------------------------------------------
// Attention epilogue
// ---------------------------------------------------------------------------
__global__ void build_kv(const float* __restrict__ refpt, float* __restrict__ kv) {
    int idx = blockIdx.x * 256 + threadIdx.x;
    if (idx >= NB * NR * CO * CO) return;
    int d = idx % CO;
    int j = (idx / CO) % (NR * CO);
    int b = idx / (CO * NR * CO);
    int r = j / CO, cc = j % CO;
    kv[idx] = refpt[(((size_t)r * NB + b) * CO + cc) * CO + d];
}

// C[b,m,c] = sum_e A[b,m,e] * W[e,c]
__global__ void gemm_aw(const float* __restrict__ A, const float* __restrict__ Wm,
                        float* __restrict__ Cm, int M)
{
    int idx = blockIdx.x * 256 + threadIdx.x;
    if (idx >= NB * M * CO) return;
    int c = idx % CO;
    int m = (idx / CO) % M;
    int b = idx / (CO * M);
    const float* ar = A + ((size_t)b * M + m) * CO;
    float acc = 0.f;
    for (int e = 0; e < CO; ++e) acc = fmaf(ar[e], Wm[e * CO + c], acc);
    Cm[idx] = acc;
}

__global__ __launch_bounds__(256) void attn_kernel(const float* __restrict__ qb,
    const float* __restrict__ kb, const float* __restrict__ vb, float* __restrict__ ctx)
{
    __shared__ float sq[CO];
    __shared__ float sl[NR * CO];
    __shared__ float red[4], red2[4];
    const int b = blockIdx.y, i = blockIdx.x;
    const int tid = threadIdx.x;
    if (tid < CO) sq[tid] = qb[((size_t)b * NK + i) * CO + tid];
    __syncthreads();
    const float scale = 0.08838834764831843f;  // 1/sqrt(128)
    for (int j = tid; j < NR * CO; j += 256) {
        const float* kr = kb + ((size_t)b * NR * CO + j) * CO;
        float d = 0.f;
        for (int e = 0; e < CO; ++e) d = fmaf(sq[e], kr[e], d);
        sl[j] = d * scale;
    }
    __syncthreads();
    float m = -1e30f;
    for (int j = tid; j < NR * CO; j += 256) m = fmaxf(m, sl[j]);
#pragma unroll
    for (int off = 32; off; off >>= 1) m = fmaxf(m, __shfl_down(m, off));
    if ((tid & 63) == 0) red[tid >> 6] = m;
    __syncthreads();
    m = fmaxf(fmaxf(red[0], red[1]), fmaxf(red[2], red[3]));
    float s = 0.f;
    for (int j = tid; j < NR * CO; j += 256) { float e = expf(sl[j] - m); sl[j] = e; s += e; }
#pragma unroll
    for (int off = 32; off; off >>= 1) s += __shfl_down(s, off);
    if ((tid & 63) == 0) red2[tid >> 6] = s;
    __syncthreads();
    const float inv = 1.f / (red2[0] + red2[1] + red2[2] + red2[3]);
    if (tid < CO) {
        float acc = 0.f;
        for (int j = 0; j < NR * CO; ++j)
            acc = fmaf(sl[j], vb[((size_t)b * NR * CO + j) * CO + tid], acc);
        ctx[((size_t)b * NK + i) * CO + tid] = acc * inv;
    }
}

// out1[b,i,c] = sum_e ctx[b,i,e]*Wo[e,c] + target_pt[b,i,c]
__global__ void final_agg(const float* __restrict__ ctx, const float* __restrict__ Wo,
                          const float* __restrict__ tpt, float* __restrict__ out1)
{
    int idx = blockIdx.x * 256 + threadIdx.x;
    if (idx >= NB * NK * CO) return;
    int c = idx % CO;
    const float* cr = ctx + (size_t)(idx / CO) * CO;
    float acc = tpt[idx];
    for (int e = 0; e < CO; ++e) acc = fmaf(cr[e], Wo[e * CO + c], acc);
    out1[idx] = acc;
}

// ---------------------------------------------------------------------------
extern "C" void kernel_launch(void* const* d_in, const int* in_sizes, int n_in,
                              void* d_out, int out_size, void* d_ws, size_t ws_size,
                              hipStream_t stream) {
    (void)in_sizes; (void)n_in; (void)out_size; (void)ws_size;
    const float* target = (const float*)d_in[0];
    const float* ref    = (const float*)d_in[1];
    const float* sqz_w  = (const float*)d_in[2];
    const float* sqz_b  = (const float*)d_in[3];
    const float* slot_w = (const float*)d_in[4];
    const float* slot_b = (const float*)d_in[5];
    const float* Wq     = (const float*)d_in[6];
    const float* Wk     = (const float*)d_in[7];
    const float* Wv     = (const float*)d_in[8];
    const float* Wo     = (const float*)d_in[9];

    float* out  = (float*)d_out;
    float* out0 = out;              // sqz_target (8,128,64,64)  == xt
    float* out1 = out + 4194304;    // agg_pt     (8,64,128)
    float* out2 = out + 4259840;    // ref_pt     (3,8,128,128)
    float* out3 = out + 4653056;    // slot_pt    (8,16,128)
    float* out4 = out + 4669440;    // slot_mask  (8,16,64,64)  == slot probs

    float* ws    = (float*)d_ws;
    float* ssb   = ws;                  //    524,288  slot conv raw
    float* xr    = ssb + 524288;        // 12,582,912  sqz_ref fp32
    float* rmax  = xr + 12582912;       //      3,072
    float* rinv  = rmax + 3072;         //      3,072
    float* cent  = rinv + 3072;         //     65,536
    float* gsums = cent + 65536;        //     65,536
    float* gcnt  = gsums + 65536;       //        512
    float* tpt   = gcnt + 512;          //     65,536  target_pt fp32
    float* kvb   = tpt + 65536;         //    393,216
    float* qb    = kvb + 393216;        //     65,536
    float* kb    = qb + 65536;          //    393,216
    float* vb    = kb + 393216;         //    393,216
    float* ctxb  = vb + 393216;         //     65,536
    // total ~14.6M floats = 58 MB

    // zero accumulators (ws/d_out are re-poisoned before every timed call)
    hipMemsetAsync(gsums, 0, (size_t)(65536 + 512 + 65536) * 4, stream);  // gsums|gcnt|tpt
    hipMemsetAsync(out3, 0, (size_t)16384 * 4, stream);                   // slot_pt accum

    // 1x1 convs
    conv1x1<64, 64, 32, 4, 4><<<dim3(NHW / 64, CO / 64, NB), 256, 0, stream>>>(
        target, sqz_w, sqz_b, out0);
    conv1x1<16, 64, 32, 1, 4><<<dim3(NHW / 64, 1, NB), 256, 0, stream>>>(
        target, slot_w, slot_b, ssb);
    conv1x1<64, 64, 32, 4, 4><<<dim3(NHW / 64, CO / 64, NR * NB), 256, 0, stream>>>(
        ref, sqz_w, sqz_b, xr);

    // kmeans (xt == out0)
    km_init<<<(NB * NK * CO + 255) / 256, 256, 0, stream>>>(out0, cent);
    for (int it = 0; it < KMITERS; ++it) {
        km_assign<<<dim3(NHW / 256, NB), 256, 0, stream>>>(out0, cent, gsums, gcnt);
        km_update<<<NB * NK, 128, 0, stream>>>(cent, gsums, gcnt);
    }
    // final assignment -> target_pt = cluster sums (unnormalized)
    km_assign<<<dim3(NHW / 256, NB), 256, 0, stream>>>(out0, cent, tpt, gcnt);

    // slot branch (probs land in out4, slot_pt accumulates in out3)
    slot_softmax<<<(NB * NHW + 255) / 256, 256, 0, stream>>>(ssb, out4);
    slot_pt_kernel<<<dim3(NHW / 256, NB), 256, 0, stream>>>(out4, out0, out3);

    // ref branch (ref_pt lands in out2)
    rowstats<<<NR * NB * CO, 256, 0, stream>>>(xr, rmax, rinv);
    refpt_gemm<<<dim3(CO / 32, CO / 32, NR * NB), 256, 0, stream>>>(xr, rmax, rinv, out2);

    // attention
    build_kv<<<(NB * NR * CO * CO + 255) / 256, 256, 0, stream>>>(out2, kvb);
    gemm_aw<<<(NB * NK * CO + 255) / 256, 256, 0, stream>>>(tpt, Wq, qb, NK);
    gemm_aw<<<(NB * NR * CO * CO + 255) / 256, 256, 0, stream>>>(kvb, Wk, kb, NR * CO);
    gemm_aw<<<(NB * NR * CO * CO + 255) / 256, 256, 0, stream>>>(kvb, Wv, vb, NR * CO);
    attn_kernel<<<dim3(NK, NB), 256, 0, stream>>>(qb, kb, vb, ctxb);
    final_agg<<<(NB * NK * CO + 255) / 256, 256, 0, stream>>>(ctxb, Wo, tpt, out1);
}

// Round 4
// 1489.532 us; speedup vs baseline: 1.5716x; 1.5716x over previous
//
#include <hip/hip_runtime.h>

#define NB 8
#define CIN 512
#define CO 128
#define NS 16
#define NHW 4096
#define NR 3
#define NK 64
#define KMITERS 10

typedef __attribute__((ext_vector_type(8))) short s16x8;
typedef __attribute__((ext_vector_type(4))) float f32x4;

// Truncating hi/lo bf16 split: x ~= hi + lo with |err| <= 2^-16 |x|.
static __device__ __forceinline__ void bsplit(float x, short& h, short& l) {
    union { float f; unsigned u; } a; a.f = x;
    h = (short)(a.u >> 16);
    union { unsigned u; float f; } hf; hf.u = a.u & 0xFFFF0000u;
    union { float f; unsigned u; } r; r.f = x - hf.f;
    l = (short)(r.u >> 16);
}

// ---------------------------------------------------------------------------
// MFMA bf16x3 1x1-conv GEMM (ref branch ONLY — smooth consumers, loose tol):
// out[g,m,n] = sum_c W[m,c]*X[g,c,n] + bias[m]
// ---------------------------------------------------------------------------
__global__ __launch_bounds__(256) void conv_mfma(const float* __restrict__ X,
    const float* __restrict__ Wt, const float* __restrict__ bias, float* __restrict__ out)
{
    __shared__ short sWh[128 * 40];  // [m][k] pad 40 (16B-aligned frag reads)
    __shared__ short sWl[128 * 40];
    __shared__ float sX[32 * 133];   // [k][n] pad 133 (conflict-free column reads)
    const int g = blockIdx.y;
    const int n0 = blockIdx.x * 128;
    const int tid = threadIdx.x;
    const int lane = tid & 63, w = tid >> 6;
    const int l15 = lane & 15, quad = lane >> 4;
    const int wm = (w & 1) * 64, wn = (w >> 1) * 64;

    f32x4 acc[4][4];
#pragma unroll
    for (int i = 0; i < 4; ++i)
#pragma unroll
        for (int j = 0; j < 4; ++j) acc[i][j] = (f32x4){0.f, 0.f, 0.f, 0.f};

    for (int c0 = 0; c0 < CIN; c0 += 32) {
        if (c0) __syncthreads();
#pragma unroll
        for (int r = 0; r < 4; ++r) {
            int e = r * 1024 + tid * 4;
            int m = e >> 5, cc = e & 31;
            const float4 wv = *(const float4*)&Wt[(size_t)m * CIN + c0 + cc];
            short h0, l0, h1, l1, h2, l2, h3, l3;
            bsplit(wv.x, h0, l0); bsplit(wv.y, h1, l1);
            bsplit(wv.z, h2, l2); bsplit(wv.w, h3, l3);
            *(short4*)&sWh[m * 40 + cc] = make_short4(h0, h1, h2, h3);
            *(short4*)&sWl[m * 40 + cc] = make_short4(l0, l1, l2, l3);
        }
#pragma unroll
        for (int r = 0; r < 4; ++r) {
            int e = r * 1024 + tid * 4;
            int k = e >> 7, n = e & 127;
            const float4 xv = *(const float4*)&X[((size_t)g * CIN + c0 + k) * NHW + n0 + n];
            float* p = &sX[k * 133 + n];
            p[0] = xv.x; p[1] = xv.y; p[2] = xv.z; p[3] = xv.w;
        }
        __syncthreads();

        s16x8 ah[4], al[4];
#pragma unroll
        for (int mt = 0; mt < 4; ++mt) {
            int m = wm + mt * 16 + l15;
            ah[mt] = *(const s16x8*)&sWh[m * 40 + quad * 8];
            al[mt] = *(const s16x8*)&sWl[m * 40 + quad * 8];
        }
#pragma unroll
        for (int nt = 0; nt < 4; ++nt) {
            int n = wn + nt * 16 + l15;
            s16x8 bh, bl;
#pragma unroll
            for (int jj = 0; jj < 8; ++jj) {
                float xv = sX[(quad * 8 + jj) * 133 + n];
                short h, l; bsplit(xv, h, l);
                bh[jj] = h; bl[jj] = l;
            }
#pragma unroll
            for (int mt = 0; mt < 4; ++mt) {
                acc[mt][nt] = __builtin_amdgcn_mfma_f32_16x16x32_bf16(ah[mt], bh, acc[mt][nt], 0, 0, 0);
                acc[mt][nt] = __builtin_amdgcn_mfma_f32_16x16x32_bf16(ah[mt], bl, acc[mt][nt], 0, 0, 0);
                acc[mt][nt] = __builtin_amdgcn_mfma_f32_16x16x32_bf16(al[mt], bh, acc[mt][nt], 0, 0, 0);
            }
        }
    }
    // C/D layout: col = lane&15, row = quad*4 + reg  [verified by R3 output0 pass]
#pragma unroll
    for (int mt = 0; mt < 4; ++mt) {
#pragma unroll
        for (int reg = 0; reg < 4; ++reg) {
            int m = wm + mt * 16 + quad * 4 + reg;
            float bv = bias[m];
#pragma unroll
            for (int nt = 0; nt < 4; ++nt) {
                int n = wn + nt * 16 + l15;
                out[((size_t)g * CO + m) * NHW + n0 + n] = acc[mt][nt][reg] + bv;
            }
        }
    }
}

// ---------------------------------------------------------------------------
// Exact fp32 VALU conv — target branch (kmeans needs <=1e-5-scale noise; this
// exact config produced ZERO label flips in R2 — do not change its tiling).
// ---------------------------------------------------------------------------
template<int BM, int BN, int BK, int TM, int TN>
__global__ __launch_bounds__(256) void conv1x1(const float* __restrict__ X,
    const float* __restrict__ Wt, const float* __restrict__ bias,
    float* __restrict__ outf)
{
    __shared__ float sW[BK][BM + 1];
    __shared__ float sX2[BK][BN + 1];
    const int g  = blockIdx.z;
    const int m0 = blockIdx.y * BM;
    const int n0 = blockIdx.x * BN;
    const int tid = threadIdx.x;
    const int tn = tid % (BN / TN);
    const int tm = tid / (BN / TN);
    const int O = gridDim.y * BM;

    float acc[TM][TN];
#pragma unroll
    for (int i = 0; i < TM; ++i)
#pragma unroll
        for (int j = 0; j < TN; ++j) acc[i][j] = 0.f;

    for (int c0 = 0; c0 < CIN; c0 += BK) {
#pragma unroll
        for (int idx = tid; idx < BM * BK; idx += 256) {
            int k = idx % BK, i = idx / BK;
            sW[k][i] = Wt[(size_t)(m0 + i) * CIN + c0 + k];
        }
#pragma unroll
        for (int idx = tid; idx < BK * BN; idx += 256) {
            int j = idx % BN, k = idx / BN;
            sX2[k][j] = X[((size_t)g * CIN + c0 + k) * NHW + n0 + j];
        }
        __syncthreads();
#pragma unroll
        for (int k = 0; k < BK; ++k) {
            float a[TM], bb[TN];
#pragma unroll
            for (int i = 0; i < TM; ++i) a[i] = sW[k][tm * TM + i];
#pragma unroll
            for (int j = 0; j < TN; ++j) bb[j] = sX2[k][tn * TN + j];
#pragma unroll
            for (int i = 0; i < TM; ++i)
#pragma unroll
                for (int j = 0; j < TN; ++j) acc[i][j] = fmaf(a[i], bb[j], acc[i][j]);
        }
        __syncthreads();
    }
#pragma unroll
    for (int i = 0; i < TM; ++i) {
        int m = m0 + tm * TM + i;
        float bv = bias[m];
#pragma unroll
        for (int j = 0; j < TN; ++j) {
            int n = n0 + tn * TN + j;
            outf[((size_t)g * O + m) * NHW + n] = acc[i][j] + bv;
        }
    }
}

// ---------------------------------------------------------------------------
// KMeans
// ---------------------------------------------------------------------------
__global__ void km_init(const float* __restrict__ xt, float* __restrict__ cent) {
    int idx = blockIdx.x * 256 + threadIdx.x;
    if (idx >= NB * NK * CO) return;
    int c = idx % CO;
    int k = (idx / CO) % NK;
    int b = idx / (CO * NK);
    cent[idx] = xt[((size_t)b * CO + c) * NHW + 65 * k];
}

// grid (32, NB), 256 thr. 128 points/block: labels + per-block partial sums.
__global__ __launch_bounds__(256) void km_label(const float* __restrict__ xt,
    const float* __restrict__ cent, float* __restrict__ psums, float* __restrict__ pcnt)
{
    __shared__ float sCent[64 * 129];  // phase1: centroids; phase2: cluster sums
    __shared__ float sXs[32 * 133];    // c-chunk of X, [c][n]
    __shared__ float sC2[64];
    __shared__ float sCnt[64];
    __shared__ int sLab[128];
    const int b = blockIdx.y, nb = blockIdx.x;
    const int n0 = nb * 128;
    const int tid = threadIdx.x;

#pragma unroll
    for (int r = 0; r < 8; ++r) {
        int e = r * 1024 + tid * 4;
        int k = e >> 7, c = e & 127;
        const float4 cv = *(const float4*)&cent[((size_t)b * NK + k) * CO + c];
        float* p = &sCent[k * 129 + c];
        p[0] = cv.x; p[1] = cv.y; p[2] = cv.z; p[3] = cv.w;
    }
    __syncthreads();
    if (tid < 64) {
        float s = 0.f;
        for (int c = 0; c < CO; ++c) { float v = sCent[tid * 129 + c]; s = fmaf(v, v, s); }
        sC2[tid] = s;
    }

    const int tn = tid & 7, tm = tid >> 3;   // 4 pts x 8 clusters per thread
    float dot[4][8];
    float p2[4];
#pragma unroll
    for (int i = 0; i < 4; ++i) {
        p2[i] = 0.f;
#pragma unroll
        for (int j = 0; j < 8; ++j) dot[i][j] = 0.f;
    }
    for (int cc = 0; cc < 4; ++cc) {
        __syncthreads();
#pragma unroll
        for (int r = 0; r < 4; ++r) {
            int e = r * 1024 + tid * 4;
            int c = e >> 7, n = e & 127;
            const float4 xv = *(const float4*)&xt[((size_t)b * CO + cc * 32 + c) * NHW + n0 + n];
            float* p = &sXs[c * 133 + n];
            p[0] = xv.x; p[1] = xv.y; p[2] = xv.z; p[3] = xv.w;
        }
        __syncthreads();
        for (int c4 = 0; c4 < 8; ++c4) {
            float xv[4][4];
#pragma unroll
            for (int j = 0; j < 4; ++j)
#pragma unroll
                for (int i = 0; i < 4; ++i)
                    xv[j][i] = sXs[(c4 * 4 + j) * 133 + tm * 4 + i];
#pragma unroll
            for (int j = 0; j < 4; ++j)
#pragma unroll
                for (int i = 0; i < 4; ++i)
                    p2[i] = fmaf(xv[j][i], xv[j][i], p2[i]);
#pragma unroll
            for (int jj = 0; jj < 8; ++jj) {
                int k = tn * 8 + jj;
#pragma unroll
                for (int j = 0; j < 4; ++j) {
                    float cv = sCent[k * 129 + cc * 32 + c4 * 4 + j];
#pragma unroll
                    for (int i = 0; i < 4; ++i)
                        dot[i][jj] = fmaf(xv[j][i], cv, dot[i][jj]);
                }
            }
        }
    }
    // argmin, first-min tie semantics (within thread ascending k, then lanes)
#pragma unroll
    for (int i = 0; i < 4; ++i) {
        int lab = tn * 8;
        float bd = p2[i] + sC2[tn * 8] - 2.f * dot[i][0];
#pragma unroll
        for (int jj = 1; jj < 8; ++jj) {
            int k = tn * 8 + jj;
            float d = p2[i] + sC2[k] - 2.f * dot[i][jj];
            if (d < bd) { bd = d; lab = k; }
        }
#pragma unroll
        for (int off = 1; off < 8; off <<= 1) {
            float d2 = __shfl_xor(bd, off);
            int l2 = __shfl_xor(lab, off);
            if (d2 < bd || (d2 == bd && l2 < lab)) { bd = d2; lab = l2; }
        }
        if (tn == 0) sLab[tm * 4 + i] = lab;
    }
    __syncthreads();
    for (int e = tid; e < 64 * 129; e += 256) sCent[e] = 0.f;
    if (tid < 64) sCnt[tid] = 0.f;
    __syncthreads();
    if (tid < 128) atomicAdd(&sCnt[sLab[tid]], 1.f);
    const int cq = tid & 31, sh = tid >> 5;
    for (int cc = 0; cc < 4; ++cc) {
        __syncthreads();
#pragma unroll
        for (int r = 0; r < 4; ++r) {
            int e = r * 1024 + tid * 4;
            int c = e >> 7, n = e & 127;
            const float4 xv = *(const float4*)&xt[((size_t)b * CO + cc * 32 + c) * NHW + n0 + n];
            float* p = &sXs[c * 133 + n];
            p[0] = xv.x; p[1] = xv.y; p[2] = xv.z; p[3] = xv.w;
        }
        __syncthreads();
        int c = cc * 32 + cq;
        for (int ii = 0; ii < 16; ++ii) {
            int p = sh * 16 + ii;
            atomicAdd(&sCent[sLab[p] * 129 + c], sXs[cq * 133 + p]);
        }
    }
    __syncthreads();
    float* ps = &psums[((size_t)b * 32 + nb) * (NK * CO)];
    for (int e = tid; e < NK * CO; e += 256) {
        int k = e >> 7, c = e & 127;
        ps[e] = sCent[k * 129 + c];
    }
    if (tid < 64) pcnt[((size_t)b * 32 + nb) * 64 + tid] = sCnt[tid];
}

// grid (NK, NB), 128 thr: reduce 32 partials; mode 0 -> centroid update, 1 -> tpt
__global__ void km_update2(float* __restrict__ cent, float* __restrict__ tpt,
    const float* __restrict__ psums, const float* __restrict__ pcnt, int mode)
{
    const int k = blockIdx.x, b = blockIdx.y, c = threadIdx.x;
    float s = 0.f;
    for (int nb = 0; nb < 32; ++nb)
        s += psums[((size_t)b * 32 + nb) * (NK * CO) + k * CO + c];
    if (mode) { tpt[((size_t)b * NK + k) * CO + c] = s; return; }
    float cn = 0.f;
    for (int nb = 0; nb < 32; ++nb)
        cn += pcnt[((size_t)b * 32 + nb) * 64 + k];
    if (cn > 0.f) cent[((size_t)b * NK + k) * CO + c] = s / fmaxf(cn, 1.f);
}

// ---------------------------------------------------------------------------
// Slot branch
// ---------------------------------------------------------------------------
__global__ void slot_softmax(const float* __restrict__ ssb, float* __restrict__ out4) {
    int idx = blockIdx.x * 256 + threadIdx.x;
    if (idx >= NB * NHW) return;
    int b = idx / NHW, n = idx % NHW;
    float v[NS];
    float m = -1e30f;
#pragma unroll
    for (int s = 0; s < NS; ++s) { v[s] = ssb[((size_t)b * NS + s) * NHW + n]; m = fmaxf(m, v[s]); }
    float sum = 0.f;
#pragma unroll
    for (int s = 0; s < NS; ++s) { v[s] = expf(v[s] - m); sum += v[s]; }
    float inv = 1.f / sum;
#pragma unroll
    for (int s = 0; s < NS; ++s)
        out4[((size_t)b * NS + s) * NHW + n] = v[s] * inv;
}

__global__ __launch_bounds__(256) void slot_pt_kernel(const float* __restrict__ ss,
    const float* __restrict__ xt, float* __restrict__ spt)
{
    __shared__ float sS[NS][257];
    __shared__ float sX2[32][257];
    const int b = blockIdx.y;
    const int n0 = blockIdx.x * 256;
    const int tid = threadIdx.x;
    for (int i = tid; i < NS * 256; i += 256) {
        int s = i >> 8, nn = i & 255;
        sS[s][nn] = ss[((size_t)b * NS + s) * NHW + n0 + nn];
    }
    const int c = tid & 31;
    const int sA = tid >> 5;
    for (int cg = 0; cg < 4; ++cg) {
        __syncthreads();
        for (int i = tid; i < 32 * 256; i += 256) {
            int cc = i >> 8, nn = i & 255;
            sX2[cc][nn] = xt[((size_t)b * CO + cg * 32 + cc) * NHW + n0 + nn];
        }
        __syncthreads();
        float a0 = 0.f, a1 = 0.f;
        for (int nn = 0; nn < 256; ++nn) {
            float x = sX2[c][nn];
            a0 = fmaf(x, sS[sA][nn], a0);
            a1 = fmaf(x, sS[sA + 8][nn], a1);
        }
        atomicAdd(&spt[((size_t)b * NS + sA) * CO + cg * 32 + c], a0);
        atomicAdd(&spt[((size_t)b * NS + sA + 8) * CO + cg * 32 + c], a1);
    }
}

// ---------------------------------------------------------------------------
// Ref branch
// ---------------------------------------------------------------------------
__global__ __launch_bounds__(256) void rowstats(const float* __restrict__ xr,
    float* __restrict__ rmax, float* __restrict__ rinv)
{
    const int row = blockIdx.x;
    const float* p = xr + (size_t)row * NHW;
    const int tid = threadIdx.x;
    float v[16];
    float m = -1e30f;
#pragma unroll
    for (int i = 0; i < 16; ++i) { v[i] = p[tid + (i << 8)]; m = fmaxf(m, v[i]); }
#pragma unroll
    for (int off = 32; off; off >>= 1) m = fmaxf(m, __shfl_down(m, off));
    __shared__ float sm[4];
    __shared__ float ss2[4];
    const int wid = tid >> 6, lane = tid & 63;
    if (lane == 0) sm[wid] = m;
    __syncthreads();
    m = fmaxf(fmaxf(sm[0], sm[1]), fmaxf(sm[2], sm[3]));
    float s = 0.f;
#pragma unroll
    for (int i = 0; i < 16; ++i) s += expf(v[i] - m);
#pragma unroll
    for (int off = 32; off; off >>= 1) s += __shfl_down(s, off);
    if (lane == 0) ss2[wid] = s;
    __syncthreads();
    if (tid == 0) {
        rmax[row] = m;
        rinv[row] = 1.f / (ss2[0] + ss2[1] + ss2[2] + ss2[3]);
    }
}

__global__ __launch_bounds__(256) void refpt_gemm(const float* __restrict__ xr,
    const float* __restrict__ rmax, const float* __restrict__ rinv,
    float* __restrict__ refpt)
{
    constexpr int BM = 32, BN = 32, BK = 64, TM = 2, TN = 2;
    __shared__ float sS[BK][BM + 1];
    __shared__ float sX2[BK][BN + 1];
    const int g = blockIdx.z;
    const int c0 = blockIdx.y * BM, d0 = blockIdx.x * BN;
    const int tid = threadIdx.x;
    const int tn = tid % (BN / TN), tm = tid / (BN / TN);
    const float* base = xr + (size_t)g * CO * NHW;
    float acc[TM][TN] = {{0.f, 0.f}, {0.f, 0.f}};
    for (int n0 = 0; n0 < NHW; n0 += BK) {
#pragma unroll
        for (int idx = tid; idx < BM * BK; idx += 256) {
            int k = idx % BK, i = idx / BK;
            int row = c0 + i;
            float vv = base[(size_t)row * NHW + n0 + k];
            sS[k][i] = expf(vv - rmax[g * CO + row]) * rinv[g * CO + row];
        }
#pragma unroll
        for (int idx = tid; idx < BN * BK; idx += 256) {
            int k = idx % BK, j = idx / BK;
            sX2[k][j] = base[(size_t)(d0 + j) * NHW + n0 + k];
        }
        __syncthreads();
#pragma unroll
        for (int k = 0; k < BK; ++k) {
            float a0 = sS[k][tm * TM], a1 = sS[k][tm * TM + 1];
            float b0 = sX2[k][tn * TN], b1 = sX2[k][tn * TN + 1];
            acc[0][0] = fmaf(a0, b0, acc[0][0]);
            acc[0][1] = fmaf(a0, b1, acc[0][1]);
            acc[1][0] = fmaf(a1, b0, acc[1][0]);
            acc[1][1] = fmaf(a1, b1, acc[1][1]);
        }
        __syncthreads();
    }
#pragma unroll
    for (int i = 0; i < TM; ++i) {
        int cc = c0 + tm * TM + i;
#pragma unroll
        for (int j = 0; j < TN; ++j) {
            int dd = d0 + tn * TN + j;
            refpt[((size_t)g * CO + cc) * CO + dd] = acc[i][j];
        }
    }
}

// ---------------------------------------------------------------------------
// Attention epilogue
// ---------------------------------------------------------------------------
__global__ void build_kv(const float* __restrict__ refpt, float* __restrict__ kv) {
    int idx = blockIdx.x * 256 + threadIdx.x;
    if (idx >= NB * NR * CO * CO) return;
    int d = idx % CO;
    int j = (idx / CO) % (NR * CO);
    int b = idx / (CO * NR * CO);
    int r = j / CO, cc = j % CO;
    kv[idx] = refpt[(((size_t)r * NB + b) * CO + cc) * CO + d];
}

__global__ void gemm_aw(const float* __restrict__ A, const float* __restrict__ Wm,
                        float* __restrict__ Cm, int M)
{
    int idx = blockIdx.x * 256 + threadIdx.x;
    if (idx >= NB * M * CO) return;
    int c = idx % CO;
    int m = (idx / CO) % M;
    int b = idx / (CO * M);
    const float* ar = A + ((size_t)b * M + m) * CO;
    float acc = 0.f;
    for (int e = 0; e < CO; ++e) acc = fmaf(ar[e], Wm[e * CO + c], acc);
    Cm[idx] = acc;
}

__global__ __launch_bounds__(256) void attn_kernel(const float* __restrict__ qb,
    const float* __restrict__ kb, const float* __restrict__ vb, float* __restrict__ ctx)
{
    __shared__ float sq[CO];
    __shared__ float sl[NR * CO];
    __shared__ float red[4], red2[4];
    const int b = blockIdx.y, i = blockIdx.x;
    const int tid = threadIdx.x;
    if (tid < CO) sq[tid] = qb[((size_t)b * NK + i) * CO + tid];
    __syncthreads();
    const float scale = 0.08838834764831843f;  // 1/sqrt(128)
    for (int j = tid; j < NR * CO; j += 256) {
        const float* kr = kb + ((size_t)b * NR * CO + j) * CO;
        float d = 0.f;
        for (int e = 0; e < CO; ++e) d = fmaf(sq[e], kr[e], d);
        sl[j] = d * scale;
    }
    __syncthreads();
    float m = -1e30f;
    for (int j = tid; j < NR * CO; j += 256) m = fmaxf(m, sl[j]);
#pragma unroll
    for (int off = 32; off; off >>= 1) m = fmaxf(m, __shfl_down(m, off));
    if ((tid & 63) == 0) red[tid >> 6] = m;
    __syncthreads();
    m = fmaxf(fmaxf(red[0], red[1]), fmaxf(red[2], red[3]));
    float s = 0.f;
    for (int j = tid; j < NR * CO; j += 256) { float e = expf(sl[j] - m); sl[j] = e; s += e; }
#pragma unroll
    for (int off = 32; off; off >>= 1) s += __shfl_down(s, off);
    if ((tid & 63) == 0) red2[tid >> 6] = s;
    __syncthreads();
    const float inv = 1.f / (red2[0] + red2[1] + red2[2] + red2[3]);
    if (tid < CO) {
        float acc = 0.f;
        for (int j = 0; j < NR * CO; ++j)
            acc = fmaf(sl[j], vb[((size_t)b * NR * CO + j) * CO + tid], acc);
        ctx[((size_t)b * NK + i) * CO + tid] = acc * inv;
    }
}

__global__ void final_agg(const float* __restrict__ ctx, const float* __restrict__ Wo,
                          const float* __restrict__ tpt, float* __restrict__ out1)
{
    int idx = blockIdx.x * 256 + threadIdx.x;
    if (idx >= NB * NK * CO) return;
    int c = idx % CO;
    const float* cr = ctx + (size_t)(idx / CO) * CO;
    float acc = tpt[idx];
    for (int e = 0; e < CO; ++e) acc = fmaf(cr[e], Wo[e * CO + c], acc);
    out1[idx] = acc;
}

// ---------------------------------------------------------------------------
extern "C" void kernel_launch(void* const* d_in, const int* in_sizes, int n_in,
                              void* d_out, int out_size, void* d_ws, size_t ws_size,
                              hipStream_t stream) {
    (void)in_sizes; (void)n_in; (void)out_size; (void)ws_size;
    const float* target = (const float*)d_in[0];
    const float* ref    = (const float*)d_in[1];
    const float* sqz_w  = (const float*)d_in[2];
    const float* sqz_b  = (const float*)d_in[3];
    const float* slot_w = (const float*)d_in[4];
    const float* slot_b = (const float*)d_in[5];
    const float* Wq     = (const float*)d_in[6];
    const float* Wk     = (const float*)d_in[7];
    const float* Wv     = (const float*)d_in[8];
    const float* Wo     = (const float*)d_in[9];

    float* out  = (float*)d_out;
    float* out0 = out;              // sqz_target (8,128,64,64)  == xt
    float* out1 = out + 4194304;    // agg_pt     (8,64,128)
    float* out2 = out + 4259840;    // ref_pt     (3,8,128,128)
    float* out3 = out + 4653056;    // slot_pt    (8,16,128)
    float* out4 = out + 4669440;    // slot_mask  (8,16,64,64)  == slot probs

    float* ws    = (float*)d_ws;
    float* ssb   = ws;                  //    524,288  slot conv raw
    float* xr    = ssb + 524288;        // 12,582,912  sqz_ref fp32
    float* rmax  = xr + 12582912;       //      3,072
    float* rinv  = rmax + 3072;         //      3,072
    float* cent  = rinv + 3072;         //     65,536
    float* psums = cent + 65536;        //  2,097,152  per-block cluster partials
    float* pcnt  = psums + 2097152;     //     16,384
    float* tpt   = pcnt + 16384;        //     65,536  target_pt fp32
    float* kvb   = tpt + 65536;         //    393,216
    float* qb    = kvb + 393216;        //     65,536
    float* kb    = qb + 65536;          //    393,216
    float* vb    = kb + 393216;         //    393,216
    float* ctxb  = vb + 393216;         //     65,536

    hipMemsetAsync(out3, 0, (size_t)16384 * 4, stream);   // slot_pt accumulator

    // convs: target = exact fp32 (kmeans-sensitive), ref = MFMA bf16x3
    conv1x1<64, 64, 32, 4, 4><<<dim3(NHW / 64, CO / 64, NB), 256, 0, stream>>>(
        target, sqz_w, sqz_b, out0);
    conv1x1<16, 64, 32, 1, 4><<<dim3(NHW / 64, 1, NB), 256, 0, stream>>>(
        target, slot_w, slot_b, ssb);
    conv_mfma<<<dim3(NHW / 128, NR * NB), 256, 0, stream>>>(ref, sqz_w, sqz_b, xr);

    // kmeans (xt == out0)
    km_init<<<(NB * NK * CO + 255) / 256, 256, 0, stream>>>(out0, cent);
    for (int it = 0; it < KMITERS; ++it) {
        km_label<<<dim3(32, NB), 256, 0, stream>>>(out0, cent, psums, pcnt);
        km_update2<<<dim3(NK, NB), 128, 0, stream>>>(cent, tpt, psums, pcnt, 0);
    }
    km_label<<<dim3(32, NB), 256, 0, stream>>>(out0, cent, psums, pcnt);
    km_update2<<<dim3(NK, NB), 128, 0, stream>>>(cent, tpt, psums, pcnt, 1);

    // slot branch (probs land in out4, slot_pt accumulates in out3)
    slot_softmax<<<(NB * NHW + 255) / 256, 256, 0, stream>>>(ssb, out4);
    slot_pt_kernel<<<dim3(NHW / 256, NB), 256, 0, stream>>>(out4, out0, out3);

    // ref branch (ref_pt lands in out2)
    rowstats<<<NR * NB * CO, 256, 0, stream>>>(xr, rmax, rinv);
    refpt_gemm<<<dim3(CO / 32, CO / 32, NR * NB), 256, 0, stream>>>(xr, rmax, rinv, out2);

    // attention
    build_kv<<<(NB * NR * CO * CO + 255) / 256, 256, 0, stream>>>(out2, kvb);
    gemm_aw<<<(NB * NK * CO + 255) / 256, 256, 0, stream>>>(tpt, Wq, qb, NK);
    gemm_aw<<<(NB * NR * CO * CO + 255) / 256, 256, 0, stream>>>(kvb, Wk, kb, NR * CO);
    gemm_aw<<<(NB * NR * CO * CO + 255) / 256, 256, 0, stream>>>(kvb, Wv, vb, NR * CO);
    attn_kernel<<<dim3(NK, NB), 256, 0, stream>>>(qb, kb, vb, ctxb);
    final_agg<<<(NB * NK * CO + 255) / 256, 256, 0, stream>>>(ctxb, Wo, tpt, out1);
}